// Round 13
// baseline (21392.766 us; speedup 1.0000x reference)
//
#include <hip/hip_runtime.h>
#include <hip/hip_cooperative_groups.h>

namespace cg = cooperative_groups;

typedef __attribute__((ext_vector_type(8))) short short8;
typedef __attribute__((ext_vector_type(4))) float f32x4;

__device__ __forceinline__ unsigned short f2bf(float f) {
  unsigned int u = __float_as_uint(f);
  u += 0x7FFFu + ((u >> 16) & 1u);
  return (unsigned short)(u >> 16);
}
__device__ __forceinline__ float bf2f(unsigned short h) {
  unsigned int u = ((unsigned int)h) << 16;
  return __uint_as_float(u);
}

// ---- coherent (agent-scope, sc0 sc1) access helpers for cross-XCD buffers ----
__device__ __forceinline__ short8 cload16(const unsigned short* p) {
  const unsigned long long* q = (const unsigned long long*)p;
  unsigned long long a = __hip_atomic_load(q, __ATOMIC_RELAXED, __HIP_MEMORY_SCOPE_AGENT);
  unsigned long long b = __hip_atomic_load(q + 1, __ATOMIC_RELAXED, __HIP_MEMORY_SCOPE_AGENT);
  union { unsigned long long u[2]; short8 v; } r;
  r.u[0] = a; r.u[1] = b;
  return r.v;
}
__device__ __forceinline__ float cloadf(const float* p) {
  return __hip_atomic_load(p, __ATOMIC_RELAXED, __HIP_MEMORY_SCOPE_AGENT);
}
__device__ __forceinline__ void cstoref(float* p, float v) {
  __hip_atomic_store(p, v, __ATOMIC_RELAXED, __HIP_MEMORY_SCOPE_AGENT);
}
__device__ __forceinline__ void cstoreu16(unsigned short* p, unsigned short v) {
  __hip_atomic_store(p, v, __ATOMIC_RELAXED, __HIP_MEMORY_SCOPE_AGENT);
}

// ------------- split pack fp32 -> (hi, lo) bf16, n % 4 == 0 -------------
__global__ __launch_bounds__(256) void pack_split_kernel(const float* __restrict__ src,
                                                         unsigned short* __restrict__ hi,
                                                         unsigned short* __restrict__ lo,
                                                         int n) {
  int i = (blockIdx.x * 256 + threadIdx.x) * 4;
  if (i >= n) return;
  float4 v = *(const float4*)(src + i);
  ushort4 h, l;
  h.x = f2bf(v.x); l.x = f2bf(v.x - bf2f(h.x));
  h.y = f2bf(v.y); l.y = f2bf(v.y - bf2f(h.y));
  h.z = f2bf(v.z); l.z = f2bf(v.z - bf2f(h.z));
  h.w = f2bf(v.w); l.w = f2bf(v.w - bf2f(h.w));
  *(ushort4*)(hi + i) = h;
  *(ushort4*)(lo + i) = l;
}

// ------- split pack + transpose: dst[n][k] = split_bf16(src[k][n]) -------
__global__ __launch_bounds__(256) void packT_split_kernel(const float* __restrict__ src,
                                                          unsigned short* __restrict__ hi,
                                                          unsigned short* __restrict__ lo,
                                                          int kbits, int N) {
  int idx = blockIdx.x * 256 + threadIdx.x;
  int K = 1 << kbits;
  int n = idx >> kbits;
  int k = idx & (K - 1);
  float v = src[k * N + n];
  unsigned short h = f2bf(v);
  hi[idx] = h;
  lo[idx] = f2bf(v - bf2f(h));
}

// ------------- plain pack + transpose: dst[n][k] = bf16(src[k][n]) -------------
__global__ __launch_bounds__(256) void packT_bf16_kernel(const float* __restrict__ src,
                                                         unsigned short* __restrict__ dst,
                                                         int kbits, int N) {
  int idx = blockIdx.x * 256 + threadIdx.x;
  int K = 1 << kbits;
  int n = idx >> kbits;
  int k = idx & (K - 1);
  dst[idx] = f2bf(src[k * N + n]);
}

// ------------- fp32 transpose 1024x1024: Wt[c][k] = W[k][c] -------------
__global__ __launch_bounds__(256) void transpose1024_kernel(const float* __restrict__ W,
                                                            float* __restrict__ Wt) {
  int idx = blockIdx.x * 256 + threadIdx.x;
  int c = idx >> 10, k = idx & 1023;
  Wt[idx] = W[k * 1024 + c];
}

// ------- split-precision MFMA GEMM: C = (Ahi+Alo) @ (Bhi+Blo)^T + bias -------
__global__ __launch_bounds__(256) void gemm_bf16x2_kernel(
    const unsigned short* __restrict__ Ahi, const unsigned short* __restrict__ Alo,
    const unsigned short* __restrict__ Bthi, const unsigned short* __restrict__ Btlo,
    const float* __restrict__ bias, float* __restrict__ C,
    int M, int N, int K) {
  __shared__ short Ah[64][40], Al[64][40], Bh[64][40], Bl[64][40];

  const int tid = threadIdx.x;
  const int wave = tid >> 6;
  const int lane = tid & 63;
  const int quad = lane >> 4;
  const int l16 = lane & 15;
  const int row0 = blockIdx.y * 64;
  const int col0 = blockIdx.x * 64;

  f32x4 acc[4];
  const f32x4 zero = {0.f, 0.f, 0.f, 0.f};
#pragma unroll
  for (int i = 0; i < 4; i++) acc[i] = zero;

  const int sr = tid >> 2;
  const int sseg = tid & 3;

  for (int k0 = 0; k0 < K; k0 += 32) {
    {
      long aoff = (long)(row0 + sr) * K + k0 + sseg * 8;
      long boff = (long)(col0 + sr) * K + k0 + sseg * 8;
      *(short8*)(&Ah[sr][sseg * 8]) = *(const short8*)(Ahi + aoff);
      *(short8*)(&Al[sr][sseg * 8]) = *(const short8*)(Alo + aoff);
      *(short8*)(&Bh[sr][sseg * 8]) = *(const short8*)(Bthi + boff);
      *(short8*)(&Bl[sr][sseg * 8]) = *(const short8*)(Btlo + boff);
    }
    __syncthreads();
    short8 ah = *(const short8*)(&Ah[wave * 16 + l16][quad * 8]);
    short8 al = *(const short8*)(&Al[wave * 16 + l16][quad * 8]);
#pragma unroll
    for (int nt = 0; nt < 4; nt++) {
      short8 bh = *(const short8*)(&Bh[nt * 16 + l16][quad * 8]);
      short8 bl = *(const short8*)(&Bl[nt * 16 + l16][quad * 8]);
      acc[nt] = __builtin_amdgcn_mfma_f32_16x16x32_bf16(al, bh, acc[nt], 0, 0, 0);
      acc[nt] = __builtin_amdgcn_mfma_f32_16x16x32_bf16(ah, bl, acc[nt], 0, 0, 0);
      acc[nt] = __builtin_amdgcn_mfma_f32_16x16x32_bf16(ah, bh, acc[nt], 0, 0, 0);
    }
    __syncthreads();
  }

#pragma unroll
  for (int nt = 0; nt < 4; nt++) {
    int col = col0 + nt * 16 + l16;
    float bv = bias[col];
#pragma unroll
    for (int r = 0; r < 4; r++) {
      int row = row0 + wave * 16 + quad * 4 + r;
      C[(long)row * N + col] = acc[nt][r] + bv;
    }
  }
}

// ---------------- plain bf16 MFMA GEMM (output projection) ----------------
__global__ __launch_bounds__(256) void gemm_bf16_kernel(
    const unsigned short* __restrict__ A,
    const unsigned short* __restrict__ Bt,
    const float* __restrict__ bias,
    float* __restrict__ C,
    int M, int N, int K, int relu) {
  __shared__ short As[64][40];
  __shared__ short Bs[64][40];

  const int tid = threadIdx.x;
  const int wave = tid >> 6;
  const int lane = tid & 63;
  const int quad = lane >> 4;
  const int l16 = lane & 15;
  const int row0 = blockIdx.y * 64;
  const int col0 = blockIdx.x * 64;

  f32x4 acc[4];
  const f32x4 zero = {0.f, 0.f, 0.f, 0.f};
#pragma unroll
  for (int i = 0; i < 4; i++) acc[i] = zero;

  const int sr = tid >> 2;
  const int sseg = tid & 3;

  for (int k0 = 0; k0 < K; k0 += 32) {
    {
      short8 va = *(const short8*)(A + (long)(row0 + sr) * K + k0 + sseg * 8);
      *(short8*)(&As[sr][sseg * 8]) = va;
      short8 vb = *(const short8*)(Bt + (long)(col0 + sr) * K + k0 + sseg * 8);
      *(short8*)(&Bs[sr][sseg * 8]) = vb;
    }
    __syncthreads();
    short8 a = *(const short8*)(&As[wave * 16 + l16][quad * 8]);
#pragma unroll
    for (int nt = 0; nt < 4; nt++) {
      short8 b = *(const short8*)(&Bs[nt * 16 + l16][quad * 8]);
      acc[nt] = __builtin_amdgcn_mfma_f32_16x16x32_bf16(a, b, acc[nt], 0, 0, 0);
    }
    __syncthreads();
  }

#pragma unroll
  for (int nt = 0; nt < 4; nt++) {
    int col = col0 + nt * 16 + l16;
    float bv = bias[col];
#pragma unroll
    for (int r = 0; r < 4; r++) {
      int row = row0 + wave * 16 + quad * 4 + r;
      float v = acc[nt][r] + bv;
      if (relu) v = fmaxf(v, 0.f);
      C[(long)row * N + col] = v;
    }
  }
}

// ---------------- MFMA cooperative recurrence ----------------
// 128 blocks x 256 threads. Blocks 0..63 (ZR): z+r gates for cols [64b..64b+15]
// (Wz,Wr split-bf16 in LDS, 132KB). Blocks 64..127 (S): s gate + h update.
//
// History: R2 27.1ms (handoff counters vs grid.sync, was 42.5); R8 23.1ms
// (sc0sc1, no L2 flush/inv); R12 20.45ms (C++-batched group loads, VGPR 108).
// R12 post-mortem: batching recovered only ~2.6us/phase -> per-load latency
// is ~200-300cy and grouped waits already near-optimal. Remaining ~17us/phase
// is HANDOFF cost. Suspect: FALSE SHARING -- syncc[0] and syncc[1] share one
// cache line, so 128 RMW signals + ~both groups' poll floods serialize in a
// single L3 slice queue every phase.
// R13 (this): (A) counters split to separate 128B lines (syncc[0], syncc[32]).
//             (B) 2-deep pipelined k-groups: issue group g+2's loads into the
//                 just-freed staging registers before consuming group g
//                 (pure C++ program order, same atomic primitives).
// Protocol/roles/addressing otherwise identical to R12 (validated).
__global__ __launch_bounds__(256) void recurrence_mfma_kernel(
    const float* __restrict__ xz, const float* __restrict__ xr, const float* __restrict__ xs,
    const float* __restrict__ Wzt, const float* __restrict__ Wrt, const float* __restrict__ Wst,
    float* __restrict__ hbuf, float* __restrict__ zbuf,
    unsigned short* __restrict__ h_hi, unsigned short* __restrict__ h_lo,
    unsigned short* __restrict__ rh_hi, unsigned short* __restrict__ rh_lo,
    unsigned short* __restrict__ hs_bf, float* __restrict__ hfin,
    unsigned int* __restrict__ syncc) {
  extern __shared__ short smem[];  // [16][1032] x4 (zr-blocks) or x2 (s-blocks)
  cg::grid_group grid = cg::this_grid();

  const int tid = threadIdx.x;
  const int wave = tid >> 6;
  const int lane = tid & 63;
  const int quad = lane >> 4;
  const int l16 = lane & 15;
  const int bid = blockIdx.x;
  const bool is_s = (bid >= 64);
  const int c0 = (bid & 63) * 16;

  // sync counters on SEPARATE 128-byte lines (R13 change A)
  unsigned int* sigZR = syncc;        // ZR-done count, line 0
  unsigned int* sigS  = syncc + 32;   // S-done count, line 1

  short* wh0 = smem;            // z (or s) hi
  short* wl0 = smem + 16512;    // z (or s) lo
  short* wh1 = smem + 33024;    // r hi
  short* wl1 = smem + 49536;    // r lo

  if (!is_s) {
    for (int i = tid; i < 16384; i += 256) {
      int n = i >> 10, k = i & 1023;
      float vz = Wzt[(c0 + n) * 1024 + k];
      unsigned short hz = f2bf(vz);
      wh0[n * 1032 + k] = (short)hz;
      wl0[n * 1032 + k] = (short)f2bf(vz - bf2f(hz));
      float vr = Wrt[(c0 + n) * 1024 + k];
      unsigned short hr = f2bf(vr);
      wh1[n * 1032 + k] = (short)hr;
      wl1[n * 1032 + k] = (short)f2bf(vr - bf2f(hr));
    }
  } else {
    for (int i = tid; i < 16384; i += 256) {
      int n = i >> 10, k = i & 1023;
      float vs = Wst[(c0 + n) * 1024 + k];
      unsigned short hs = f2bf(vs);
      wh0[n * 1032 + k] = (short)hs;
      wl0[n * 1032 + k] = (short)f2bf(vs - bf2f(hs));
    }
    // zero-init h for this block's columns (ws is poisoned)
    for (int i = tid; i < 1024; i += 256) {
      int row = i >> 4, col = c0 + (i & 15);
      hbuf[row * 1024 + col] = 0.f;
      h_hi[row * 1024 + col] = 0;
      h_lo[row * 1024 + col] = 0;
    }
  }
  // counters re-zeroed every launch (workspace may be poisoned between runs)
  if (bid == 0 && tid == 0) { syncc[0] = 0u; syncc[32] = 0u; }
  __threadfence();
  grid.sync();  // one-time: weights staged, h zeroed, counters zeroed (wbl2 publishes to L3)

  const int aoff = (wave * 16 + l16) * 1024 + quad * 8;  // A-frag: row=lane&15 (+wave*16), k=quad*8+j
  const int boff = l16 * 1032 + quad * 8;                // B-frag from LDS [n][k]
  const int crow = wave * 16 + quad * 4;                 // C rows crow..crow+3
  const int col = c0 + l16;                              // C col

// R13 change B: 2-deep pipelined staging. BUF is A or B; KG is k-base.
#define LOAD_GRP(SRC_HI, SRC_LO, BUF, KG)                      \
  _Pragma("unroll")                                            \
  for (int j = 0; j < 8; j++) {                                \
    sh##BUF[j] = cload16(SRC_HI + aoff + (KG) + j * 32);       \
    sl##BUF[j] = cload16(SRC_LO + aoff + (KG) + j * 32);       \
  }

  for (int t = 0; t < 512; t++) {
    if (!is_s) {
      // ---- phase 1: z and r ----
      float xzv[4], xrv[4], holdv[4];
#pragma unroll
      for (int rr = 0; rr < 4; rr++) {
        const int rowg = crow + rr;
        const long xoff = ((long)rowg * 512 + t) * 1024 + col;
        xzv[rr] = xz[xoff];
        xrv[rr] = xr[xoff];
        holdv[rr] = cloadf(&hbuf[rowg * 1024 + col]);
      }
      f32x4 accz = {0.f, 0.f, 0.f, 0.f};
      f32x4 accr = {0.f, 0.f, 0.f, 0.f};
      short8 shA[8], slA[8], shB[8], slB[8];
      LOAD_GRP(h_hi, h_lo, A, 0)       // G0
      LOAD_GRP(h_hi, h_lo, B, 256)     // G1 in flight behind G0
#define ZR_CONSUME(BUF, KG)                                                       \
  _Pragma("unroll")                                                               \
  for (int j = 0; j < 8; j++) {                                                   \
    const int k0 = (KG) + j * 32;                                                 \
    short8 bzh = *(const short8*)(wh0 + boff + k0);                               \
    short8 bzl = *(const short8*)(wl0 + boff + k0);                               \
    short8 brh = *(const short8*)(wh1 + boff + k0);                               \
    short8 brl = *(const short8*)(wl1 + boff + k0);                               \
    accz = __builtin_amdgcn_mfma_f32_16x16x32_bf16(sl##BUF[j], bzh, accz, 0, 0, 0); \
    accz = __builtin_amdgcn_mfma_f32_16x16x32_bf16(sh##BUF[j], bzl, accz, 0, 0, 0); \
    accz = __builtin_amdgcn_mfma_f32_16x16x32_bf16(sh##BUF[j], bzh, accz, 0, 0, 0); \
    accr = __builtin_amdgcn_mfma_f32_16x16x32_bf16(sl##BUF[j], brh, accr, 0, 0, 0); \
    accr = __builtin_amdgcn_mfma_f32_16x16x32_bf16(sh##BUF[j], brl, accr, 0, 0, 0); \
    accr = __builtin_amdgcn_mfma_f32_16x16x32_bf16(sh##BUF[j], brh, accr, 0, 0, 0); \
  }
      ZR_CONSUME(A, 0)                 // consume G0 (waits only G0)
      LOAD_GRP(h_hi, h_lo, A, 512)     // G2 into freed A regs
      ZR_CONSUME(B, 256)               // consume G1
      LOAD_GRP(h_hi, h_lo, B, 768)     // G3 into freed B regs
      ZR_CONSUME(A, 512)               // consume G2
      ZR_CONSUME(B, 768)               // consume G3
#undef ZR_CONSUME
#pragma unroll
      for (int rr = 0; rr < 4; rr++) {
        int rowg = crow + rr;
        float zv = 1.f / (1.f + __expf(-(accz[rr] + xzv[rr])));
        cstoref(&zbuf[rowg * 1024 + col], zv);
        float rv = 1.f / (1.f + __expf(-(accr[rr] + xrv[rr])));
        float rh = rv * holdv[rr];
        unsigned short hi = f2bf(rh);
        cstoreu16(&rh_hi[rowg * 1024 + col], hi);
        cstoreu16(&rh_lo[rowg * 1024 + col], f2bf(rh - bf2f(hi)));
      }
      // release: stores ack'd at L3, then signal ZR-done for step t
      asm volatile("s_waitcnt vmcnt(0)" ::: "memory");
      __syncthreads();
      if (tid == 0)
        __hip_atomic_fetch_add(sigZR, 1u, __ATOMIC_RELAXED, __HIP_MEMORY_SCOPE_AGENT);
      // wait for S group's h_t before starting step t+1
      if (t != 511) {
        if (tid == 0) {
          unsigned tgt = 64u * (unsigned)(t + 1);
          while (__hip_atomic_load(sigS, __ATOMIC_RELAXED, __HIP_MEMORY_SCOPE_AGENT) < tgt)
            __builtin_amdgcn_s_sleep(4);
        }
        __syncthreads();  // h reads are sc0 sc1 -> no stale L1/L2 possible
      }
    } else {
      // wait for all 64 ZR blocks' z/rh of step t
      if (tid == 0) {
        unsigned tgt = 64u * (unsigned)(t + 1);
        while (__hip_atomic_load(sigZR, __ATOMIC_RELAXED, __HIP_MEMORY_SCOPE_AGENT) < tgt)
          __builtin_amdgcn_s_sleep(4);
      }
      __syncthreads();  // rh/z reads are sc0 sc1 -> no stale L1/L2 possible

      // ---- phase 2: s gate + h update ----
      float xsv[4], zvv[4], holdv[4];
#pragma unroll
      for (int rr = 0; rr < 4; rr++) {
        const int rowg = crow + rr;
        const long xoff = ((long)rowg * 512 + t) * 1024 + col;
        xsv[rr] = xs[xoff];
        zvv[rr] = cloadf(&zbuf[rowg * 1024 + col]);
        holdv[rr] = cloadf(&hbuf[rowg * 1024 + col]);
      }
      f32x4 accs = {0.f, 0.f, 0.f, 0.f};
      short8 shA[8], slA[8], shB[8], slB[8];
      LOAD_GRP(rh_hi, rh_lo, A, 0)
      LOAD_GRP(rh_hi, rh_lo, B, 256)
#define S_CONSUME(BUF, KG)                                                        \
  _Pragma("unroll")                                                               \
  for (int j = 0; j < 8; j++) {                                                   \
    const int k0 = (KG) + j * 32;                                                 \
    short8 bh = *(const short8*)(wh0 + boff + k0);                                \
    short8 bl = *(const short8*)(wl0 + boff + k0);                                \
    accs = __builtin_amdgcn_mfma_f32_16x16x32_bf16(sl##BUF[j], bh, accs, 0, 0, 0); \
    accs = __builtin_amdgcn_mfma_f32_16x16x32_bf16(sh##BUF[j], bl, accs, 0, 0, 0); \
    accs = __builtin_amdgcn_mfma_f32_16x16x32_bf16(sh##BUF[j], bh, accs, 0, 0, 0); \
  }
      S_CONSUME(A, 0)
      LOAD_GRP(rh_hi, rh_lo, A, 512)
      S_CONSUME(B, 256)
      LOAD_GRP(rh_hi, rh_lo, B, 768)
      S_CONSUME(A, 512)
      S_CONSUME(B, 768)
#undef S_CONSUME
#pragma unroll
      for (int rr = 0; rr < 4; rr++) {
        int rowg = crow + rr;
        long xoff = ((long)rowg * 512 + t) * 1024 + col;
        float st = tanhf(accs[rr] + xsv[rr]);
        float hn = (1.f - zvv[rr]) * holdv[rr] + zvv[rr] * st;
        cstoref(&hbuf[rowg * 1024 + col], hn);
        unsigned short hi = f2bf(hn);
        cstoreu16(&h_hi[rowg * 1024 + col], hi);
        cstoreu16(&h_lo[rowg * 1024 + col], f2bf(hn - bf2f(hi)));
        hs_bf[xoff] = f2bf(hn);                 // consumed after kernel boundary
        if (t == 511) hfin[rowg * 1024 + col] = hn;  // same
      }
      // release: stores ack'd at L3, then signal S-done for step t
      asm volatile("s_waitcnt vmcnt(0)" ::: "memory");
      __syncthreads();
      if (tid == 0)
        __hip_atomic_fetch_add(sigS, 1u, __ATOMIC_RELAXED, __HIP_MEMORY_SCOPE_AGENT);
    }
  }
#undef LOAD_GRP
}

// ---------------- launch ----------------
extern "C" void kernel_launch(void* const* d_in, const int* in_sizes, int n_in,
                              void* d_out, int out_size, void* d_ws, size_t ws_size,
                              hipStream_t stream) {
  const float* inputs = (const float*)d_in[0];
  const float* Wz = (const float*)d_in[1];
  const float* bz = (const float*)d_in[2];
  const float* Wr = (const float*)d_in[3];
  const float* br = (const float*)d_in[4];
  const float* Ws = (const float*)d_in[5];
  const float* bs = (const float*)d_in[6];
  const float* Wo = (const float*)d_in[7];
  const float* bo = (const float*)d_in[8];

  // Workspace layout, top = 491782276 B (~469 MiB; R1 proved >= 497.5 MiB exists).
  // hs_bf ALIASES Xhi/Xlo (dead after x-proj GEMMs).
  char* w = (char*)d_ws;
  float* xz = (float*)(w + 0ll);
  float* xr = (float*)(w + 134217728ll);
  float* xs = (float*)(w + 268435456ll);
  unsigned short* Xhi = (unsigned short*)(w + 402653184ll);
  unsigned short* Xlo = (unsigned short*)(w + 436207616ll);
  unsigned short* hs_bf = (unsigned short*)(w + 402653184ll);  // alias
  unsigned short* WzxThi = (unsigned short*)(w + 469762048ll);
  unsigned short* WzxTlo = (unsigned short*)(w + 470810624ll);
  unsigned short* WrxThi = (unsigned short*)(w + 471859200ll);
  unsigned short* WrxTlo = (unsigned short*)(w + 472907776ll);
  unsigned short* WsxThi = (unsigned short*)(w + 473956352ll);
  unsigned short* WsxTlo = (unsigned short*)(w + 475004928ll);
  unsigned short* WoT = (unsigned short*)(w + 476053504ll);
  float* Wzt = (float*)(w + 478150656ll);
  float* Wrt = (float*)(w + 482344960ll);
  float* Wst = (float*)(w + 486539264ll);
  float* hbuf = (float*)(w + 490733568ll);
  float* zbuf = (float*)(w + 490995712ll);
  unsigned short* h_hi = (unsigned short*)(w + 491257856ll);
  unsigned short* h_lo = (unsigned short*)(w + 491388928ll);
  unsigned short* rh_hi = (unsigned short*)(w + 491520000ll);
  unsigned short* rh_lo = (unsigned short*)(w + 491651072ll);
  unsigned int* syncc = (unsigned int*)(w + 491782144ll);  // 2 counters on separate 128B lines

  float* out = (float*)d_out;
  float* hfin = out + 33554432;  // 64*512*1024

  hipLaunchKernelGGL(pack_split_kernel, dim3(16384), dim3(256), 0, stream,
                     inputs, Xhi, Xlo, 16777216);
  hipLaunchKernelGGL(packT_split_kernel, dim3(2048), dim3(256), 0, stream,
                     Wz + 1048576, WzxThi, WzxTlo, 9, 1024);
  hipLaunchKernelGGL(packT_split_kernel, dim3(2048), dim3(256), 0, stream,
                     Wr + 1048576, WrxThi, WrxTlo, 9, 1024);
  hipLaunchKernelGGL(packT_split_kernel, dim3(2048), dim3(256), 0, stream,
                     Ws + 1048576, WsxThi, WsxTlo, 9, 1024);
  hipLaunchKernelGGL(packT_bf16_kernel, dim3(4096), dim3(256), 0, stream, Wo, WoT, 10, 1024);
  hipLaunchKernelGGL(transpose1024_kernel, dim3(4096), dim3(256), 0, stream, Wz, Wzt);
  hipLaunchKernelGGL(transpose1024_kernel, dim3(4096), dim3(256), 0, stream, Wr, Wrt);
  hipLaunchKernelGGL(transpose1024_kernel, dim3(4096), dim3(256), 0, stream, Ws, Wst);

  hipLaunchKernelGGL(gemm_bf16x2_kernel, dim3(16, 512), dim3(256), 0, stream,
                     Xhi, Xlo, WzxThi, WzxTlo, bz, xz, 32768, 1024, 512);
  hipLaunchKernelGGL(gemm_bf16x2_kernel, dim3(16, 512), dim3(256), 0, stream,
                     Xhi, Xlo, WrxThi, WrxTlo, br, xr, 32768, 1024, 512);
  hipLaunchKernelGGL(gemm_bf16x2_kernel, dim3(16, 512), dim3(256), 0, stream,
                     Xhi, Xlo, WsxThi, WsxTlo, bs, xs, 32768, 1024, 512);

  // MFMA recurrence: 128 blocks, 132096 B dynamic LDS (4 x [16][1032] shorts)
  void* args[] = {&xz, &xr, &xs, &Wzt, &Wrt, &Wst, &hbuf, &zbuf,
                  &h_hi, &h_lo, &rh_hi, &rh_lo, &hs_bf, &hfin, &syncc};
  hipLaunchCooperativeKernel((const void*)recurrence_mfma_kernel, dim3(128), dim3(256),
                             args, 132096, stream);

  hipLaunchKernelGGL(gemm_bf16_kernel, dim3(16, 512), dim3(256), 0, stream,
                     hs_bf, WoT, bo, out, 32768, 1024, 1024, 1);
}

// Round 14
// 18708.365 us; speedup vs baseline: 1.1435x; 1.1435x over previous
//
#include <hip/hip_runtime.h>
#include <hip/hip_cooperative_groups.h>

namespace cg = cooperative_groups;

typedef __attribute__((ext_vector_type(8))) short short8;
typedef __attribute__((ext_vector_type(4))) float f32x4;

__device__ __forceinline__ unsigned short f2bf(float f) {
  unsigned int u = __float_as_uint(f);
  u += 0x7FFFu + ((u >> 16) & 1u);
  return (unsigned short)(u >> 16);
}
__device__ __forceinline__ float bf2f(unsigned short h) {
  unsigned int u = ((unsigned int)h) << 16;
  return __uint_as_float(u);
}

// ---- coherent (agent-scope, sc0 sc1) access helpers for cross-XCD buffers ----
__device__ __forceinline__ short8 cload16(const unsigned short* p) {
  const unsigned long long* q = (const unsigned long long*)p;
  unsigned long long a = __hip_atomic_load(q, __ATOMIC_RELAXED, __HIP_MEMORY_SCOPE_AGENT);
  unsigned long long b = __hip_atomic_load(q + 1, __ATOMIC_RELAXED, __HIP_MEMORY_SCOPE_AGENT);
  union { unsigned long long u[2]; short8 v; } r;
  r.u[0] = a; r.u[1] = b;
  return r.v;
}
__device__ __forceinline__ float cloadf(const float* p) {
  return __hip_atomic_load(p, __ATOMIC_RELAXED, __HIP_MEMORY_SCOPE_AGENT);
}
__device__ __forceinline__ void cstoref(float* p, float v) {
  __hip_atomic_store(p, v, __ATOMIC_RELAXED, __HIP_MEMORY_SCOPE_AGENT);
}
__device__ __forceinline__ void cstoreu16(unsigned short* p, unsigned short v) {
  __hip_atomic_store(p, v, __ATOMIC_RELAXED, __HIP_MEMORY_SCOPE_AGENT);
}
__device__ __forceinline__ void cstoreu32(unsigned int* p, unsigned int v) {
  __hip_atomic_store(p, v, __ATOMIC_RELAXED, __HIP_MEMORY_SCOPE_AGENT);
}
__device__ __forceinline__ unsigned int cloadu32(const unsigned int* p) {
  return __hip_atomic_load(p, __ATOMIC_RELAXED, __HIP_MEMORY_SCOPE_AGENT);
}

// ------------- split pack fp32 -> (hi, lo) bf16, n % 4 == 0 -------------
__global__ __launch_bounds__(256) void pack_split_kernel(const float* __restrict__ src,
                                                         unsigned short* __restrict__ hi,
                                                         unsigned short* __restrict__ lo,
                                                         int n) {
  int i = (blockIdx.x * 256 + threadIdx.x) * 4;
  if (i >= n) return;
  float4 v = *(const float4*)(src + i);
  ushort4 h, l;
  h.x = f2bf(v.x); l.x = f2bf(v.x - bf2f(h.x));
  h.y = f2bf(v.y); l.y = f2bf(v.y - bf2f(h.y));
  h.z = f2bf(v.z); l.z = f2bf(v.z - bf2f(h.z));
  h.w = f2bf(v.w); l.w = f2bf(v.w - bf2f(h.w));
  *(ushort4*)(hi + i) = h;
  *(ushort4*)(lo + i) = l;
}

// ------- split pack + transpose: dst[n][k] = split_bf16(src[k][n]) -------
__global__ __launch_bounds__(256) void packT_split_kernel(const float* __restrict__ src,
                                                          unsigned short* __restrict__ hi,
                                                          unsigned short* __restrict__ lo,
                                                          int kbits, int N) {
  int idx = blockIdx.x * 256 + threadIdx.x;
  int K = 1 << kbits;
  int n = idx >> kbits;
  int k = idx & (K - 1);
  float v = src[k * N + n];
  unsigned short h = f2bf(v);
  hi[idx] = h;
  lo[idx] = f2bf(v - bf2f(h));
}

// ------------- plain pack + transpose: dst[n][k] = bf16(src[k][n]) -------------
__global__ __launch_bounds__(256) void packT_bf16_kernel(const float* __restrict__ src,
                                                         unsigned short* __restrict__ dst,
                                                         int kbits, int N) {
  int idx = blockIdx.x * 256 + threadIdx.x;
  int K = 1 << kbits;
  int n = idx >> kbits;
  int k = idx & (K - 1);
  dst[idx] = f2bf(src[k * N + n]);
}

// ------------- fp32 transpose 1024x1024: Wt[c][k] = W[k][c] -------------
__global__ __launch_bounds__(256) void transpose1024_kernel(const float* __restrict__ W,
                                                            float* __restrict__ Wt) {
  int idx = blockIdx.x * 256 + threadIdx.x;
  int c = idx >> 10, k = idx & 1023;
  Wt[idx] = W[k * 1024 + c];
}

// ------- split-precision MFMA GEMM: C = (Ahi+Alo) @ (Bhi+Blo)^T + bias -------
__global__ __launch_bounds__(256) void gemm_bf16x2_kernel(
    const unsigned short* __restrict__ Ahi, const unsigned short* __restrict__ Alo,
    const unsigned short* __restrict__ Bthi, const unsigned short* __restrict__ Btlo,
    const float* __restrict__ bias, float* __restrict__ C,
    int M, int N, int K) {
  __shared__ short Ah[64][40], Al[64][40], Bh[64][40], Bl[64][40];

  const int tid = threadIdx.x;
  const int wave = tid >> 6;
  const int lane = tid & 63;
  const int quad = lane >> 4;
  const int l16 = lane & 15;
  const int row0 = blockIdx.y * 64;
  const int col0 = blockIdx.x * 64;

  f32x4 acc[4];
  const f32x4 zero = {0.f, 0.f, 0.f, 0.f};
#pragma unroll
  for (int i = 0; i < 4; i++) acc[i] = zero;

  const int sr = tid >> 2;
  const int sseg = tid & 3;

  for (int k0 = 0; k0 < K; k0 += 32) {
    {
      long aoff = (long)(row0 + sr) * K + k0 + sseg * 8;
      long boff = (long)(col0 + sr) * K + k0 + sseg * 8;
      *(short8*)(&Ah[sr][sseg * 8]) = *(const short8*)(Ahi + aoff);
      *(short8*)(&Al[sr][sseg * 8]) = *(const short8*)(Alo + aoff);
      *(short8*)(&Bh[sr][sseg * 8]) = *(const short8*)(Bthi + boff);
      *(short8*)(&Bl[sr][sseg * 8]) = *(const short8*)(Btlo + boff);
    }
    __syncthreads();
    short8 ah = *(const short8*)(&Ah[wave * 16 + l16][quad * 8]);
    short8 al = *(const short8*)(&Al[wave * 16 + l16][quad * 8]);
#pragma unroll
    for (int nt = 0; nt < 4; nt++) {
      short8 bh = *(const short8*)(&Bh[nt * 16 + l16][quad * 8]);
      short8 bl = *(const short8*)(&Bl[nt * 16 + l16][quad * 8]);
      acc[nt] = __builtin_amdgcn_mfma_f32_16x16x32_bf16(al, bh, acc[nt], 0, 0, 0);
      acc[nt] = __builtin_amdgcn_mfma_f32_16x16x32_bf16(ah, bl, acc[nt], 0, 0, 0);
      acc[nt] = __builtin_amdgcn_mfma_f32_16x16x32_bf16(ah, bh, acc[nt], 0, 0, 0);
    }
    __syncthreads();
  }

#pragma unroll
  for (int nt = 0; nt < 4; nt++) {
    int col = col0 + nt * 16 + l16;
    float bv = bias[col];
#pragma unroll
    for (int r = 0; r < 4; r++) {
      int row = row0 + wave * 16 + quad * 4 + r;
      C[(long)row * N + col] = acc[nt][r] + bv;
    }
  }
}

// ---------------- plain bf16 MFMA GEMM (output projection) ----------------
__global__ __launch_bounds__(256) void gemm_bf16_kernel(
    const unsigned short* __restrict__ A,
    const unsigned short* __restrict__ Bt,
    const float* __restrict__ bias,
    float* __restrict__ C,
    int M, int N, int K, int relu) {
  __shared__ short As[64][40];
  __shared__ short Bs[64][40];

  const int tid = threadIdx.x;
  const int wave = tid >> 6;
  const int lane = tid & 63;
  const int quad = lane >> 4;
  const int l16 = lane & 15;
  const int row0 = blockIdx.y * 64;
  const int col0 = blockIdx.x * 64;

  f32x4 acc[4];
  const f32x4 zero = {0.f, 0.f, 0.f, 0.f};
#pragma unroll
  for (int i = 0; i < 4; i++) acc[i] = zero;

  const int sr = tid >> 2;
  const int sseg = tid & 3;

  for (int k0 = 0; k0 < K; k0 += 32) {
    {
      short8 va = *(const short8*)(A + (long)(row0 + sr) * K + k0 + sseg * 8);
      *(short8*)(&As[sr][sseg * 8]) = va;
      short8 vb = *(const short8*)(Bt + (long)(col0 + sr) * K + k0 + sseg * 8);
      *(short8*)(&Bs[sr][sseg * 8]) = vb;
    }
    __syncthreads();
    short8 a = *(const short8*)(&As[wave * 16 + l16][quad * 8]);
#pragma unroll
    for (int nt = 0; nt < 4; nt++) {
      short8 b = *(const short8*)(&Bs[nt * 16 + l16][quad * 8]);
      acc[nt] = __builtin_amdgcn_mfma_f32_16x16x32_bf16(a, b, acc[nt], 0, 0, 0);
    }
    __syncthreads();
  }

#pragma unroll
  for (int nt = 0; nt < 4; nt++) {
    int col = col0 + nt * 16 + l16;
    float bv = bias[col];
#pragma unroll
    for (int r = 0; r < 4; r++) {
      int row = row0 + wave * 16 + quad * 4 + r;
      float v = acc[nt][r] + bv;
      if (relu) v = fmaxf(v, 0.f);
      C[(long)row * N + col] = v;
    }
  }
}

// ---------------- MFMA cooperative recurrence ----------------
// 128 blocks x 256 threads. Blocks 0..63 (ZR): z+r gates for cols [64b..64b+15]
// (Wz,Wr split-bf16 in LDS, 132KB). Blocks 64..127 (S): s gate + h update.
//
// History: R2 27.1ms (handoff vs grid.sync); R8 23.1ms (sc0sc1, no L2
// flush/inv); R12 20.45ms (batched group loads); R13 20.47ms NEUTRAL
// (counter line-split + 2-deep pipeline both no-ops) -> false-sharing and
// load-pipelining theories dead. Remaining ~17us/phase = handoff protocol:
// (1) 64 same-address atomicAdd RMWs serialize at one L3 slice (~4-8us);
// (2) 64 pollers flood that line, RMWs queue behind the flood.
// R14 (this): NO shared counters. Per-producer epoch flags on private 128B
// lines: producer's tid0 stores done[bid]=t+1 after the (unchanged)
// vmcnt(0)+syncthreads release. Consumer's wave0 polls all 64 flags with a
// single 64-lane gather + __all(v>=t+1) -- no atomics, no hot line, one
// L3 round trip per poll. K-loop body identical to R13 (measured).
__global__ __launch_bounds__(256) void recurrence_mfma_kernel(
    const float* __restrict__ xz, const float* __restrict__ xr, const float* __restrict__ xs,
    const float* __restrict__ Wzt, const float* __restrict__ Wrt, const float* __restrict__ Wst,
    float* __restrict__ hbuf, float* __restrict__ zbuf,
    unsigned short* __restrict__ h_hi, unsigned short* __restrict__ h_lo,
    unsigned short* __restrict__ rh_hi, unsigned short* __restrict__ rh_lo,
    unsigned short* __restrict__ hs_bf, float* __restrict__ hfin,
    unsigned int* __restrict__ syncc) {
  extern __shared__ short smem[];  // [16][1032] x4 (zr-blocks) or x2 (s-blocks)
  cg::grid_group grid = cg::this_grid();

  const int tid = threadIdx.x;
  const int wave = tid >> 6;
  const int lane = tid & 63;
  const int quad = lane >> 4;
  const int l16 = lane & 15;
  const int bid = blockIdx.x;
  const bool is_s = (bid >= 64);
  const int c0 = (bid & 63) * 16;

  // R14: per-producer epoch flags, one 128B line each.
  // doneZ[i*32]: ZR block i finished step (value = t+1)
  // doneS[i*32]: S block i finished step
  unsigned int* doneZ = syncc;           // 64 lines
  unsigned int* doneS = syncc + 64 * 32; // 64 lines

  short* wh0 = smem;            // z (or s) hi
  short* wl0 = smem + 16512;    // z (or s) lo
  short* wh1 = smem + 33024;    // r hi
  short* wl1 = smem + 49536;    // r lo

  if (!is_s) {
    for (int i = tid; i < 16384; i += 256) {
      int n = i >> 10, k = i & 1023;
      float vz = Wzt[(c0 + n) * 1024 + k];
      unsigned short hz = f2bf(vz);
      wh0[n * 1032 + k] = (short)hz;
      wl0[n * 1032 + k] = (short)f2bf(vz - bf2f(hz));
      float vr = Wrt[(c0 + n) * 1024 + k];
      unsigned short hr = f2bf(vr);
      wh1[n * 1032 + k] = (short)hr;
      wl1[n * 1032 + k] = (short)f2bf(vr - bf2f(hr));
    }
  } else {
    for (int i = tid; i < 16384; i += 256) {
      int n = i >> 10, k = i & 1023;
      float vs = Wst[(c0 + n) * 1024 + k];
      unsigned short hs = f2bf(vs);
      wh0[n * 1032 + k] = (short)hs;
      wl0[n * 1032 + k] = (short)f2bf(vs - bf2f(hs));
    }
    // zero-init h for this block's columns (ws is poisoned)
    for (int i = tid; i < 1024; i += 256) {
      int row = i >> 4, col = c0 + (i & 15);
      hbuf[row * 1024 + col] = 0.f;
      h_hi[row * 1024 + col] = 0;
      h_lo[row * 1024 + col] = 0;
    }
  }
  // flags re-zeroed every launch (workspace may be poisoned between runs)
  if (bid == 0) {
    if (tid < 64) doneZ[tid * 32] = 0u;
    else if (tid < 128) doneS[(tid - 64) * 32] = 0u;
  }
  __threadfence();
  grid.sync();  // one-time: weights staged, h zeroed, flags zeroed (wbl2 publishes to L3)

  const int aoff = (wave * 16 + l16) * 1024 + quad * 8;  // A-frag: row=lane&15 (+wave*16), k=quad*8+j
  const int boff = l16 * 1032 + quad * 8;                // B-frag from LDS [n][k]
  const int crow = wave * 16 + quad * 4;                 // C rows crow..crow+3
  const int col = c0 + l16;                              // C col

// 2-deep pipelined staging (kept from R13; measured neutral, harmless).
#define LOAD_GRP(SRC_HI, SRC_LO, BUF, KG)                      \
  _Pragma("unroll")                                            \
  for (int j = 0; j < 8; j++) {                                \
    sh##BUF[j] = cload16(SRC_HI + aoff + (KG) + j * 32);       \
    sl##BUF[j] = cload16(SRC_LO + aoff + (KG) + j * 32);       \
  }

  for (int t = 0; t < 512; t++) {
    if (!is_s) {
      // ---- phase 1: z and r ----
      float xzv[4], xrv[4], holdv[4];
#pragma unroll
      for (int rr = 0; rr < 4; rr++) {
        const int rowg = crow + rr;
        const long xoff = ((long)rowg * 512 + t) * 1024 + col;
        xzv[rr] = xz[xoff];
        xrv[rr] = xr[xoff];
        holdv[rr] = cloadf(&hbuf[rowg * 1024 + col]);
      }
      f32x4 accz = {0.f, 0.f, 0.f, 0.f};
      f32x4 accr = {0.f, 0.f, 0.f, 0.f};
      short8 shA[8], slA[8], shB[8], slB[8];
      LOAD_GRP(h_hi, h_lo, A, 0)       // G0
      LOAD_GRP(h_hi, h_lo, B, 256)     // G1 in flight behind G0
#define ZR_CONSUME(BUF, KG)                                                       \
  _Pragma("unroll")                                                               \
  for (int j = 0; j < 8; j++) {                                                   \
    const int k0 = (KG) + j * 32;                                                 \
    short8 bzh = *(const short8*)(wh0 + boff + k0);                               \
    short8 bzl = *(const short8*)(wl0 + boff + k0);                               \
    short8 brh = *(const short8*)(wh1 + boff + k0);                               \
    short8 brl = *(const short8*)(wl1 + boff + k0);                               \
    accz = __builtin_amdgcn_mfma_f32_16x16x32_bf16(sl##BUF[j], bzh, accz, 0, 0, 0); \
    accz = __builtin_amdgcn_mfma_f32_16x16x32_bf16(sh##BUF[j], bzl, accz, 0, 0, 0); \
    accz = __builtin_amdgcn_mfma_f32_16x16x32_bf16(sh##BUF[j], bzh, accz, 0, 0, 0); \
    accr = __builtin_amdgcn_mfma_f32_16x16x32_bf16(sl##BUF[j], brh, accr, 0, 0, 0); \
    accr = __builtin_amdgcn_mfma_f32_16x16x32_bf16(sh##BUF[j], brl, accr, 0, 0, 0); \
    accr = __builtin_amdgcn_mfma_f32_16x16x32_bf16(sh##BUF[j], brh, accr, 0, 0, 0); \
  }
      ZR_CONSUME(A, 0)                 // consume G0 (waits only G0)
      LOAD_GRP(h_hi, h_lo, A, 512)     // G2 into freed A regs
      ZR_CONSUME(B, 256)               // consume G1
      LOAD_GRP(h_hi, h_lo, B, 768)     // G3 into freed B regs
      ZR_CONSUME(A, 512)               // consume G2
      ZR_CONSUME(B, 768)               // consume G3
#undef ZR_CONSUME
#pragma unroll
      for (int rr = 0; rr < 4; rr++) {
        int rowg = crow + rr;
        float zv = 1.f / (1.f + __expf(-(accz[rr] + xzv[rr])));
        cstoref(&zbuf[rowg * 1024 + col], zv);
        float rv = 1.f / (1.f + __expf(-(accr[rr] + xrv[rr])));
        float rh = rv * holdv[rr];
        unsigned short hi = f2bf(rh);
        cstoreu16(&rh_hi[rowg * 1024 + col], hi);
        cstoreu16(&rh_lo[rowg * 1024 + col], f2bf(rh - bf2f(hi)));
      }
      // release: stores ack'd at L3, then publish ZR-done for step t (private line)
      asm volatile("s_waitcnt vmcnt(0)" ::: "memory");
      __syncthreads();
      if (tid == 0) cstoreu32(&doneZ[(bid & 63) * 32], (unsigned)(t + 1));
      // wait for ALL S blocks' h_t before starting step t+1 (wave-0 gather poll)
      if (t != 511) {
        if (tid < 64) {
          const unsigned tgt = (unsigned)(t + 1);
          while (!__all((int)(cloadu32(&doneS[tid * 32]) >= tgt)))
            __builtin_amdgcn_s_sleep(8);
        }
        __syncthreads();  // h reads are sc0 sc1 -> no stale L1/L2 possible
      }
    } else {
      // wait for ALL 64 ZR blocks' z/rh of step t (wave-0 gather poll)
      if (tid < 64) {
        const unsigned tgt = (unsigned)(t + 1);
        while (!__all((int)(cloadu32(&doneZ[tid * 32]) >= tgt)))
          __builtin_amdgcn_s_sleep(8);
      }
      __syncthreads();  // rh/z reads are sc0 sc1 -> no stale L1/L2 possible

      // ---- phase 2: s gate + h update ----
      float xsv[4], zvv[4], holdv[4];
#pragma unroll
      for (int rr = 0; rr < 4; rr++) {
        const int rowg = crow + rr;
        const long xoff = ((long)rowg * 512 + t) * 1024 + col;
        xsv[rr] = xs[xoff];
        zvv[rr] = cloadf(&zbuf[rowg * 1024 + col]);
        holdv[rr] = cloadf(&hbuf[rowg * 1024 + col]);
      }
      f32x4 accs = {0.f, 0.f, 0.f, 0.f};
      short8 shA[8], slA[8], shB[8], slB[8];
      LOAD_GRP(rh_hi, rh_lo, A, 0)
      LOAD_GRP(rh_hi, rh_lo, B, 256)
#define S_CONSUME(BUF, KG)                                                        \
  _Pragma("unroll")                                                               \
  for (int j = 0; j < 8; j++) {                                                   \
    const int k0 = (KG) + j * 32;                                                 \
    short8 bh = *(const short8*)(wh0 + boff + k0);                                \
    short8 bl = *(const short8*)(wl0 + boff + k0);                                \
    accs = __builtin_amdgcn_mfma_f32_16x16x32_bf16(sl##BUF[j], bh, accs, 0, 0, 0); \
    accs = __builtin_amdgcn_mfma_f32_16x16x32_bf16(sh##BUF[j], bl, accs, 0, 0, 0); \
    accs = __builtin_amdgcn_mfma_f32_16x16x32_bf16(sh##BUF[j], bh, accs, 0, 0, 0); \
  }
      S_CONSUME(A, 0)
      LOAD_GRP(rh_hi, rh_lo, A, 512)
      S_CONSUME(B, 256)
      LOAD_GRP(rh_hi, rh_lo, B, 768)
      S_CONSUME(A, 512)
      S_CONSUME(B, 768)
#undef S_CONSUME
#pragma unroll
      for (int rr = 0; rr < 4; rr++) {
        int rowg = crow + rr;
        long xoff = ((long)rowg * 512 + t) * 1024 + col;
        float st = tanhf(accs[rr] + xsv[rr]);
        float hn = (1.f - zvv[rr]) * holdv[rr] + zvv[rr] * st;
        cstoref(&hbuf[rowg * 1024 + col], hn);
        unsigned short hi = f2bf(hn);
        cstoreu16(&h_hi[rowg * 1024 + col], hi);
        cstoreu16(&h_lo[rowg * 1024 + col], f2bf(hn - bf2f(hi)));
        hs_bf[xoff] = f2bf(hn);                 // consumed after kernel boundary
        if (t == 511) hfin[rowg * 1024 + col] = hn;  // same
      }
      // release: stores ack'd at L3, then publish S-done for step t (private line)
      asm volatile("s_waitcnt vmcnt(0)" ::: "memory");
      __syncthreads();
      if (tid == 0) cstoreu32(&doneS[(bid & 63) * 32], (unsigned)(t + 1));
    }
  }
#undef LOAD_GRP
}

// ---------------- launch ----------------
extern "C" void kernel_launch(void* const* d_in, const int* in_sizes, int n_in,
                              void* d_out, int out_size, void* d_ws, size_t ws_size,
                              hipStream_t stream) {
  const float* inputs = (const float*)d_in[0];
  const float* Wz = (const float*)d_in[1];
  const float* bz = (const float*)d_in[2];
  const float* Wr = (const float*)d_in[3];
  const float* br = (const float*)d_in[4];
  const float* Ws = (const float*)d_in[5];
  const float* bs = (const float*)d_in[6];
  const float* Wo = (const float*)d_in[7];
  const float* bo = (const float*)d_in[8];

  // Workspace layout, top = 491798528 B (~469 MiB; R1 proved >= 497.5 MiB exists).
  // hs_bf ALIASES Xhi/Xlo (dead after x-proj GEMMs).
  char* w = (char*)d_ws;
  float* xz = (float*)(w + 0ll);
  float* xr = (float*)(w + 134217728ll);
  float* xs = (float*)(w + 268435456ll);
  unsigned short* Xhi = (unsigned short*)(w + 402653184ll);
  unsigned short* Xlo = (unsigned short*)(w + 436207616ll);
  unsigned short* hs_bf = (unsigned short*)(w + 402653184ll);  // alias
  unsigned short* WzxThi = (unsigned short*)(w + 469762048ll);
  unsigned short* WzxTlo = (unsigned short*)(w + 470810624ll);
  unsigned short* WrxThi = (unsigned short*)(w + 471859200ll);
  unsigned short* WrxTlo = (unsigned short*)(w + 472907776ll);
  unsigned short* WsxThi = (unsigned short*)(w + 473956352ll);
  unsigned short* WsxTlo = (unsigned short*)(w + 475004928ll);
  unsigned short* WoT = (unsigned short*)(w + 476053504ll);
  float* Wzt = (float*)(w + 478150656ll);
  float* Wrt = (float*)(w + 482344960ll);
  float* Wst = (float*)(w + 486539264ll);
  float* hbuf = (float*)(w + 490733568ll);
  float* zbuf = (float*)(w + 490995712ll);
  unsigned short* h_hi = (unsigned short*)(w + 491257856ll);
  unsigned short* h_lo = (unsigned short*)(w + 491388928ll);
  unsigned short* rh_hi = (unsigned short*)(w + 491520000ll);
  unsigned short* rh_lo = (unsigned short*)(w + 491651072ll);
  unsigned int* syncc = (unsigned int*)(w + 491782144ll);  // 128 epoch flags x 128B = 16KB

  float* out = (float*)d_out;
  float* hfin = out + 33554432;  // 64*512*1024

  hipLaunchKernelGGL(pack_split_kernel, dim3(16384), dim3(256), 0, stream,
                     inputs, Xhi, Xlo, 16777216);
  hipLaunchKernelGGL(packT_split_kernel, dim3(2048), dim3(256), 0, stream,
                     Wz + 1048576, WzxThi, WzxTlo, 9, 1024);
  hipLaunchKernelGGL(packT_split_kernel, dim3(2048), dim3(256), 0, stream,
                     Wr + 1048576, WrxThi, WrxTlo, 9, 1024);
  hipLaunchKernelGGL(packT_split_kernel, dim3(2048), dim3(256), 0, stream,
                     Ws + 1048576, WsxThi, WsxTlo, 9, 1024);
  hipLaunchKernelGGL(packT_bf16_kernel, dim3(4096), dim3(256), 0, stream, Wo, WoT, 10, 1024);
  hipLaunchKernelGGL(transpose1024_kernel, dim3(4096), dim3(256), 0, stream, Wz, Wzt);
  hipLaunchKernelGGL(transpose1024_kernel, dim3(4096), dim3(256), 0, stream, Wr, Wrt);
  hipLaunchKernelGGL(transpose1024_kernel, dim3(4096), dim3(256), 0, stream, Ws, Wst);

  hipLaunchKernelGGL(gemm_bf16x2_kernel, dim3(16, 512), dim3(256), 0, stream,
                     Xhi, Xlo, WzxThi, WzxTlo, bz, xz, 32768, 1024, 512);
  hipLaunchKernelGGL(gemm_bf16x2_kernel, dim3(16, 512), dim3(256), 0, stream,
                     Xhi, Xlo, WrxThi, WrxTlo, br, xr, 32768, 1024, 512);
  hipLaunchKernelGGL(gemm_bf16x2_kernel, dim3(16, 512), dim3(256), 0, stream,
                     Xhi, Xlo, WsxThi, WsxTlo, bs, xs, 32768, 1024, 512);

  // MFMA recurrence: 128 blocks, 132096 B dynamic LDS (4 x [16][1032] shorts)
  void* args[] = {&xz, &xr, &xs, &Wzt, &Wrt, &Wst, &hbuf, &zbuf,
                  &h_hi, &h_lo, &rh_hi, &rh_lo, &hs_bf, &hfin, &syncc};
  hipLaunchCooperativeKernel((const void*)recurrence_mfma_kernel, dim3(128), dim3(256),
                             args, 132096, stream);

  hipLaunchKernelGGL(gemm_bf16_kernel, dim3(16, 512), dim3(256), 0, stream,
                     hs_bf, WoT, bo, out, 32768, 1024, 1024, 1);
}

// Round 17
// 12693.185 us; speedup vs baseline: 1.6854x; 1.4739x over previous
//
#include <hip/hip_runtime.h>
#include <hip/hip_cooperative_groups.h>

namespace cg = cooperative_groups;

typedef __attribute__((ext_vector_type(8))) short short8;
typedef __attribute__((ext_vector_type(4))) float f32x4;

__device__ __forceinline__ unsigned short f2bf(float f) {
  unsigned int u = __float_as_uint(f);
  u += 0x7FFFu + ((u >> 16) & 1u);
  return (unsigned short)(u >> 16);
}
__device__ __forceinline__ float bf2f(unsigned short h) {
  unsigned int u = ((unsigned int)h) << 16;
  return __uint_as_float(u);
}

// ---- coherent (agent-scope, sc0 sc1) access helpers ----
// Stores: write-through past L1/L2, visible at L3 (no dirty lines -> no wbl2
// needed on release; vmcnt(0) == globally visible).
// Loads: used only for small scalar state; BULK k-loop loads are now normal
// cached loads, made safe by a per-phase buffer_inv acquire (R15).
__device__ __forceinline__ float cloadf(const float* p) {
  return __hip_atomic_load(p, __ATOMIC_RELAXED, __HIP_MEMORY_SCOPE_AGENT);
}
__device__ __forceinline__ void cstoref(float* p, float v) {
  __hip_atomic_store(p, v, __ATOMIC_RELAXED, __HIP_MEMORY_SCOPE_AGENT);
}
__device__ __forceinline__ void cstoreu16(unsigned short* p, unsigned short v) {
  __hip_atomic_store(p, v, __ATOMIC_RELAXED, __HIP_MEMORY_SCOPE_AGENT);
}
__device__ __forceinline__ void cstoreu32(unsigned int* p, unsigned int v) {
  __hip_atomic_store(p, v, __ATOMIC_RELAXED, __HIP_MEMORY_SCOPE_AGENT);
}
__device__ __forceinline__ unsigned int cloadu32(const unsigned int* p) {
  return __hip_atomic_load(p, __ATOMIC_RELAXED, __HIP_MEMORY_SCOPE_AGENT);
}

// ------------- split pack fp32 -> (hi, lo) bf16, n % 4 == 0 -------------
__global__ __launch_bounds__(256) void pack_split_kernel(const float* __restrict__ src,
                                                         unsigned short* __restrict__ hi,
                                                         unsigned short* __restrict__ lo,
                                                         int n) {
  int i = (blockIdx.x * 256 + threadIdx.x) * 4;
  if (i >= n) return;
  float4 v = *(const float4*)(src + i);
  ushort4 h, l;
  h.x = f2bf(v.x); l.x = f2bf(v.x - bf2f(h.x));
  h.y = f2bf(v.y); l.y = f2bf(v.y - bf2f(h.y));
  h.z = f2bf(v.z); l.z = f2bf(v.z - bf2f(h.z));
  h.w = f2bf(v.w); l.w = f2bf(v.w - bf2f(h.w));
  *(ushort4*)(hi + i) = h;
  *(ushort4*)(lo + i) = l;
}

// ------- split pack + transpose: dst[n][k] = split_bf16(src[k][n]) -------
__global__ __launch_bounds__(256) void packT_split_kernel(const float* __restrict__ src,
                                                          unsigned short* __restrict__ hi,
                                                          unsigned short* __restrict__ lo,
                                                          int kbits, int N) {
  int idx = blockIdx.x * 256 + threadIdx.x;
  int K = 1 << kbits;
  int n = idx >> kbits;
  int k = idx & (K - 1);
  float v = src[k * N + n];
  unsigned short h = f2bf(v);
  hi[idx] = h;
  lo[idx] = f2bf(v - bf2f(h));
}

// ------------- plain pack + transpose: dst[n][k] = bf16(src[k][n]) -------------
__global__ __launch_bounds__(256) void packT_bf16_kernel(const float* __restrict__ src,
                                                         unsigned short* __restrict__ dst,
                                                         int kbits, int N) {
  int idx = blockIdx.x * 256 + threadIdx.x;
  int K = 1 << kbits;
  int n = idx >> kbits;
  int k = idx & (K - 1);
  dst[idx] = f2bf(src[k * N + n]);
}

// ------------- fp32 transpose 1024x1024: Wt[c][k] = W[k][c] -------------
__global__ __launch_bounds__(256) void transpose1024_kernel(const float* __restrict__ W,
                                                            float* __restrict__ Wt) {
  int idx = blockIdx.x * 256 + threadIdx.x;
  int c = idx >> 10, k = idx & 1023;
  Wt[idx] = W[k * 1024 + c];
}

// ------- split-precision MFMA GEMM: C = (Ahi+Alo) @ (Bhi+Blo)^T + bias -------
__global__ __launch_bounds__(256) void gemm_bf16x2_kernel(
    const unsigned short* __restrict__ Ahi, const unsigned short* __restrict__ Alo,
    const unsigned short* __restrict__ Bthi, const unsigned short* __restrict__ Btlo,
    const float* __restrict__ bias, float* __restrict__ C,
    int M, int N, int K) {
  __shared__ short Ah[64][40], Al[64][40], Bh[64][40], Bl[64][40];

  const int tid = threadIdx.x;
  const int wave = tid >> 6;
  const int lane = tid & 63;
  const int quad = lane >> 4;
  const int l16 = lane & 15;
  const int row0 = blockIdx.y * 64;
  const int col0 = blockIdx.x * 64;

  f32x4 acc[4];
  const f32x4 zero = {0.f, 0.f, 0.f, 0.f};
#pragma unroll
  for (int i = 0; i < 4; i++) acc[i] = zero;

  const int sr = tid >> 2;
  const int sseg = tid & 3;

  for (int k0 = 0; k0 < K; k0 += 32) {
    {
      long aoff = (long)(row0 + sr) * K + k0 + sseg * 8;
      long boff = (long)(col0 + sr) * K + k0 + sseg * 8;
      *(short8*)(&Ah[sr][sseg * 8]) = *(const short8*)(Ahi + aoff);
      *(short8*)(&Al[sr][sseg * 8]) = *(const short8*)(Alo + aoff);
      *(short8*)(&Bh[sr][sseg * 8]) = *(const short8*)(Bthi + boff);
      *(short8*)(&Bl[sr][sseg * 8]) = *(const short8*)(Btlo + boff);
    }
    __syncthreads();
    short8 ah = *(const short8*)(&Ah[wave * 16 + l16][quad * 8]);
    short8 al = *(const short8*)(&Al[wave * 16 + l16][quad * 8]);
#pragma unroll
    for (int nt = 0; nt < 4; nt++) {
      short8 bh = *(const short8*)(&Bh[nt * 16 + l16][quad * 8]);
      short8 bl = *(const short8*)(&Bl[nt * 16 + l16][quad * 8]);
      acc[nt] = __builtin_amdgcn_mfma_f32_16x16x32_bf16(al, bh, acc[nt], 0, 0, 0);
      acc[nt] = __builtin_amdgcn_mfma_f32_16x16x32_bf16(ah, bl, acc[nt], 0, 0, 0);
      acc[nt] = __builtin_amdgcn_mfma_f32_16x16x32_bf16(ah, bh, acc[nt], 0, 0, 0);
    }
    __syncthreads();
  }

#pragma unroll
  for (int nt = 0; nt < 4; nt++) {
    int col = col0 + nt * 16 + l16;
    float bv = bias[col];
#pragma unroll
    for (int r = 0; r < 4; r++) {
      int row = row0 + wave * 16 + quad * 4 + r;
      C[(long)row * N + col] = acc[nt][r] + bv;
    }
  }
}

// ---------------- plain bf16 MFMA GEMM (output projection) ----------------
__global__ __launch_bounds__(256) void gemm_bf16_kernel(
    const unsigned short* __restrict__ A,
    const unsigned short* __restrict__ Bt,
    const float* __restrict__ bias,
    float* __restrict__ C,
    int M, int N, int K, int relu) {
  __shared__ short As[64][40];
  __shared__ short Bs[64][40];

  const int tid = threadIdx.x;
  const int wave = tid >> 6;
  const int lane = tid & 63;
  const int quad = lane >> 4;
  const int l16 = lane & 15;
  const int row0 = blockIdx.y * 64;
  const int col0 = blockIdx.x * 64;

  f32x4 acc[4];
  const f32x4 zero = {0.f, 0.f, 0.f, 0.f};
#pragma unroll
  for (int i = 0; i < 4; i++) acc[i] = zero;

  const int sr = tid >> 2;
  const int sseg = tid & 3;

  for (int k0 = 0; k0 < K; k0 += 32) {
    {
      short8 va = *(const short8*)(A + (long)(row0 + sr) * K + k0 + sseg * 8);
      *(short8*)(&As[sr][sseg * 8]) = va;
      short8 vb = *(const short8*)(Bt + (long)(col0 + sr) * K + k0 + sseg * 8);
      *(short8*)(&Bs[sr][sseg * 8]) = vb;
    }
    __syncthreads();
    short8 a = *(const short8*)(&As[wave * 16 + l16][quad * 8]);
#pragma unroll
    for (int nt = 0; nt < 4; nt++) {
      short8 b = *(const short8*)(&Bs[nt * 16 + l16][quad * 8]);
      acc[nt] = __builtin_amdgcn_mfma_f32_16x16x32_bf16(a, b, acc[nt], 0, 0, 0);
    }
    __syncthreads();
  }

#pragma unroll
  for (int nt = 0; nt < 4; nt++) {
    int col = col0 + nt * 16 + l16;
    float bv = bias[col];
#pragma unroll
    for (int r = 0; r < 4; r++) {
      int row = row0 + wave * 16 + quad * 4 + r;
      float v = acc[nt][r] + bv;
      if (relu) v = fmaxf(v, 0.f);
      C[(long)row * N + col] = v;
    }
  }
}

// ---------------- MFMA cooperative recurrence ----------------
// 128 blocks x 256 threads. Blocks 0..63 (ZR): z+r gates for cols [64b..64b+15]
// (Wz,Wr split-bf16 in LDS, 132KB). Blocks 64..127 (S): s gate + h update.
//
// History: R2 27.1ms; R8 23.1ms (sc0sc1, no fences); R12 20.45 (batched
// loads, only -2.6us/phase); R13 neutral; R14 17.68 (per-producer flags,
// -2.7us/phase). Residual ~14us/phase of pure vmem stall at MfmaUtil 1.4%.
// All contention theories dead -> suspect: sc0sc1 BYPASS loads have low
// sustainable outstanding-request throughput (batching barely helped).
// R15..R17 (this; R15/R16 were infra timeouts): k-loop bulk loads switched
// to NORMAL CACHED loads (full 63-outstanding pipelining). Coherence:
// producers still store sc0sc1 (write-through, at L3 when vmcnt(0) clears,
// no dirty lines); consumers, after observing flags, issue buffer_inv
// sc0 sc1 per wave (drops stale CLEAN L1/L2 copies; dirty lines e.g. hs_bf
// are preserved -- same behavior LLVM's agent-acquire relies on). Also:
// ZR wait moved to loop top (protocol-equivalent) and hs_bf/hfin stores
// moved after the flag publish (off the release-drain path).
__global__ __launch_bounds__(256) void recurrence_mfma_kernel(
    const float* __restrict__ xz, const float* __restrict__ xr, const float* __restrict__ xs,
    const float* __restrict__ Wzt, const float* __restrict__ Wrt, const float* __restrict__ Wst,
    float* __restrict__ hbuf, float* __restrict__ zbuf,
    unsigned short* __restrict__ h_hi, unsigned short* __restrict__ h_lo,
    unsigned short* __restrict__ rh_hi, unsigned short* __restrict__ rh_lo,
    unsigned short* __restrict__ hs_bf, float* __restrict__ hfin,
    unsigned int* __restrict__ syncc) {
  extern __shared__ short smem[];  // [16][1032] x4 (zr-blocks) or x2 (s-blocks)
  cg::grid_group grid = cg::this_grid();

  const int tid = threadIdx.x;
  const int wave = tid >> 6;
  const int lane = tid & 63;
  const int quad = lane >> 4;
  const int l16 = lane & 15;
  const int bid = blockIdx.x;
  const bool is_s = (bid >= 64);
  const int c0 = (bid & 63) * 16;

  // per-producer epoch flags, one 128B line each (R14, validated)
  unsigned int* doneZ = syncc;           // 64 lines
  unsigned int* doneS = syncc + 64 * 32; // 64 lines

  short* wh0 = smem;            // z (or s) hi
  short* wl0 = smem + 16512;    // z (or s) lo
  short* wh1 = smem + 33024;    // r hi
  short* wl1 = smem + 49536;    // r lo

  if (!is_s) {
    for (int i = tid; i < 16384; i += 256) {
      int n = i >> 10, k = i & 1023;
      float vz = Wzt[(c0 + n) * 1024 + k];
      unsigned short hz = f2bf(vz);
      wh0[n * 1032 + k] = (short)hz;
      wl0[n * 1032 + k] = (short)f2bf(vz - bf2f(hz));
      float vr = Wrt[(c0 + n) * 1024 + k];
      unsigned short hr = f2bf(vr);
      wh1[n * 1032 + k] = (short)hr;
      wl1[n * 1032 + k] = (short)f2bf(vr - bf2f(hr));
    }
  } else {
    for (int i = tid; i < 16384; i += 256) {
      int n = i >> 10, k = i & 1023;
      float vs = Wst[(c0 + n) * 1024 + k];
      unsigned short hs = f2bf(vs);
      wh0[n * 1032 + k] = (short)hs;
      wl0[n * 1032 + k] = (short)f2bf(vs - bf2f(hs));
    }
    // zero-init h for this block's columns (ws is poisoned)
    for (int i = tid; i < 1024; i += 256) {
      int row = i >> 4, col = c0 + (i & 15);
      hbuf[row * 1024 + col] = 0.f;
      h_hi[row * 1024 + col] = 0;
      h_lo[row * 1024 + col] = 0;
    }
  }
  // flags re-zeroed every launch (workspace may be poisoned between runs)
  if (bid == 0) {
    if (tid < 64) doneZ[tid * 32] = 0u;
    else if (tid < 128) doneS[(tid - 64) * 32] = 0u;
  }
  __threadfence();
  grid.sync();  // one-time: weights staged, h zeroed, flags zeroed

  const int aoff = (wave * 16 + l16) * 1024 + quad * 8;  // A-frag: row=lane&15 (+wave*16), k=quad*8+j
  const int boff = l16 * 1032 + quad * 8;                // B-frag from LDS [n][k]
  const int crow = wave * 16 + quad * 4;                 // C rows crow..crow+3
  const int col = c0 + l16;                              // C col

// R15: bulk staging via NORMAL CACHED loads (deep pipelining); acquire inv
// at phase start guarantees freshness.
#define LOAD_GRP(SRC_HI, SRC_LO, BUF, KG)                           \
  _Pragma("unroll")                                                 \
  for (int j = 0; j < 8; j++) {                                     \
    sh##BUF[j] = *(const short8*)(SRC_HI + aoff + (KG) + j * 32);   \
    sl##BUF[j] = *(const short8*)(SRC_LO + aoff + (KG) + j * 32);   \
  }

  for (int t = 0; t < 512; t++) {
    if (!is_s) {
      // ---- phase 1: z and r ----
      // wait for ALL S blocks' h_{t-1} (t=0: flags are 0, passes immediately)
      if (tid < 64) {
        const unsigned tgt = (unsigned)t;
        while (!__all((int)(cloadu32(&doneS[tid * 32]) >= tgt)))
          __builtin_amdgcn_s_sleep(8);
      }
      __syncthreads();
      // acquire: drop stale clean L1/L2 lines; per-wave so each wave's
      // subsequent loads are queue-ordered after its own inv
      asm volatile("buffer_inv sc0 sc1" ::: "memory");

      float xzv[4], xrv[4], holdv[4];
#pragma unroll
      for (int rr = 0; rr < 4; rr++) {
        const int rowg = crow + rr;
        const long xoff = ((long)rowg * 512 + t) * 1024 + col;
        xzv[rr] = xz[xoff];
        xrv[rr] = xr[xoff];
        holdv[rr] = cloadf(&hbuf[rowg * 1024 + col]);
      }
      f32x4 accz = {0.f, 0.f, 0.f, 0.f};
      f32x4 accr = {0.f, 0.f, 0.f, 0.f};
      short8 shA[8], slA[8], shB[8], slB[8];
      LOAD_GRP(h_hi, h_lo, A, 0)       // G0
      LOAD_GRP(h_hi, h_lo, B, 256)     // G1 in flight behind G0
#define ZR_CONSUME(BUF, KG)                                                       \
  _Pragma("unroll")                                                               \
  for (int j = 0; j < 8; j++) {                                                   \
    const int k0 = (KG) + j * 32;                                                 \
    short8 bzh = *(const short8*)(wh0 + boff + k0);                               \
    short8 bzl = *(const short8*)(wl0 + boff + k0);                               \
    short8 brh = *(const short8*)(wh1 + boff + k0);                               \
    short8 brl = *(const short8*)(wl1 + boff + k0);                               \
    accz = __builtin_amdgcn_mfma_f32_16x16x32_bf16(sl##BUF[j], bzh, accz, 0, 0, 0); \
    accz = __builtin_amdgcn_mfma_f32_16x16x32_bf16(sh##BUF[j], bzl, accz, 0, 0, 0); \
    accz = __builtin_amdgcn_mfma_f32_16x16x32_bf16(sh##BUF[j], bzh, accz, 0, 0, 0); \
    accr = __builtin_amdgcn_mfma_f32_16x16x32_bf16(sl##BUF[j], brh, accr, 0, 0, 0); \
    accr = __builtin_amdgcn_mfma_f32_16x16x32_bf16(sh##BUF[j], brl, accr, 0, 0, 0); \
    accr = __builtin_amdgcn_mfma_f32_16x16x32_bf16(sh##BUF[j], brh, accr, 0, 0, 0); \
  }
      ZR_CONSUME(A, 0)
      LOAD_GRP(h_hi, h_lo, A, 512)
      ZR_CONSUME(B, 256)
      LOAD_GRP(h_hi, h_lo, B, 768)
      ZR_CONSUME(A, 512)
      ZR_CONSUME(B, 768)
#undef ZR_CONSUME
#pragma unroll
      for (int rr = 0; rr < 4; rr++) {
        int rowg = crow + rr;
        float zv = 1.f / (1.f + __expf(-(accz[rr] + xzv[rr])));
        cstoref(&zbuf[rowg * 1024 + col], zv);
        float rv = 1.f / (1.f + __expf(-(accr[rr] + xrv[rr])));
        float rh = rv * holdv[rr];
        unsigned short hi = f2bf(rh);
        cstoreu16(&rh_hi[rowg * 1024 + col], hi);
        cstoreu16(&rh_lo[rowg * 1024 + col], f2bf(rh - bf2f(hi)));
      }
      // release: sc0sc1 stores ack'd at L3, then publish ZR-done for step t
      asm volatile("s_waitcnt vmcnt(0)" ::: "memory");
      __syncthreads();
      if (tid == 0) cstoreu32(&doneZ[(bid & 63) * 32], (unsigned)(t + 1));
    } else {
      // wait for ALL 64 ZR blocks' z/rh of step t
      if (tid < 64) {
        const unsigned tgt = (unsigned)(t + 1);
        while (!__all((int)(cloadu32(&doneZ[tid * 32]) >= tgt)))
          __builtin_amdgcn_s_sleep(8);
      }
      __syncthreads();
      asm volatile("buffer_inv sc0 sc1" ::: "memory");

      // ---- phase 2: s gate + h update ----
      float xsv[4], zvv[4], holdv[4];
#pragma unroll
      for (int rr = 0; rr < 4; rr++) {
        const int rowg = crow + rr;
        const long xoff = ((long)rowg * 512 + t) * 1024 + col;
        xsv[rr] = xs[xoff];
        zvv[rr] = cloadf(&zbuf[rowg * 1024 + col]);
        holdv[rr] = cloadf(&hbuf[rowg * 1024 + col]);
      }
      f32x4 accs = {0.f, 0.f, 0.f, 0.f};
      short8 shA[8], slA[8], shB[8], slB[8];
      LOAD_GRP(rh_hi, rh_lo, A, 0)
      LOAD_GRP(rh_hi, rh_lo, B, 256)
#define S_CONSUME(BUF, KG)                                                        \
  _Pragma("unroll")                                                               \
  for (int j = 0; j < 8; j++) {                                                   \
    const int k0 = (KG) + j * 32;                                                 \
    short8 bh = *(const short8*)(wh0 + boff + k0);                                \
    short8 bl = *(const short8*)(wl0 + boff + k0);                                \
    accs = __builtin_amdgcn_mfma_f32_16x16x32_bf16(sl##BUF[j], bh, accs, 0, 0, 0); \
    accs = __builtin_amdgcn_mfma_f32_16x16x32_bf16(sh##BUF[j], bl, accs, 0, 0, 0); \
    accs = __builtin_amdgcn_mfma_f32_16x16x32_bf16(sh##BUF[j], bh, accs, 0, 0, 0); \
  }
      S_CONSUME(A, 0)
      LOAD_GRP(rh_hi, rh_lo, A, 512)
      S_CONSUME(B, 256)
      LOAD_GRP(rh_hi, rh_lo, B, 768)
      S_CONSUME(A, 512)
      S_CONSUME(B, 768)
#undef S_CONSUME
      float hnv[4];
#pragma unroll
      for (int rr = 0; rr < 4; rr++) {
        int rowg = crow + rr;
        float st = tanhf(accs[rr] + xsv[rr]);
        float hn = (1.f - zvv[rr]) * holdv[rr] + zvv[rr] * st;
        hnv[rr] = hn;
        cstoref(&hbuf[rowg * 1024 + col], hn);
        unsigned short hi = f2bf(hn);
        cstoreu16(&h_hi[rowg * 1024 + col], hi);
        cstoreu16(&h_lo[rowg * 1024 + col], f2bf(hn - bf2f(hi)));
      }
      // release: sc0sc1 stores ack'd at L3, then publish S-done for step t
      asm volatile("s_waitcnt vmcnt(0)" ::: "memory");
      __syncthreads();
      if (tid == 0) cstoreu32(&doneS[(bid & 63) * 32], (unsigned)(t + 1));
      // hs_bf/hfin are consumed only after kernel end: store AFTER the
      // publish so their write-allocate latency is off the critical path.
#pragma unroll
      for (int rr = 0; rr < 4; rr++) {
        int rowg = crow + rr;
        long xoff = ((long)rowg * 512 + t) * 1024 + col;
        hs_bf[xoff] = f2bf(hnv[rr]);
        if (t == 511) hfin[rowg * 1024 + col] = hnv[rr];
      }
    }
  }
#undef LOAD_GRP
}

// ---------------- launch ----------------
extern "C" void kernel_launch(void* const* d_in, const int* in_sizes, int n_in,
                              void* d_out, int out_size, void* d_ws, size_t ws_size,
                              hipStream_t stream) {
  const float* inputs = (const float*)d_in[0];
  const float* Wz = (const float*)d_in[1];
  const float* bz = (const float*)d_in[2];
  const float* Wr = (const float*)d_in[3];
  const float* br = (const float*)d_in[4];
  const float* Ws = (const float*)d_in[5];
  const float* bs = (const float*)d_in[6];
  const float* Wo = (const float*)d_in[7];
  const float* bo = (const float*)d_in[8];

  // Workspace layout, top = 491798528 B (~469 MiB).
  // hs_bf ALIASES Xhi/Xlo (dead after x-proj GEMMs).
  char* w = (char*)d_ws;
  float* xz = (float*)(w + 0ll);
  float* xr = (float*)(w + 134217728ll);
  float* xs = (float*)(w + 268435456ll);
  unsigned short* Xhi = (unsigned short*)(w + 402653184ll);
  unsigned short* Xlo = (unsigned short*)(w + 436207616ll);
  unsigned short* hs_bf = (unsigned short*)(w + 402653184ll);  // alias
  unsigned short* WzxThi = (unsigned short*)(w + 469762048ll);
  unsigned short* WzxTlo = (unsigned short*)(w + 470810624ll);
  unsigned short* WrxThi = (unsigned short*)(w + 471859200ll);
  unsigned short* WrxTlo = (unsigned short*)(w + 472907776ll);
  unsigned short* WsxThi = (unsigned short*)(w + 473956352ll);
  unsigned short* WsxTlo = (unsigned short*)(w + 475004928ll);
  unsigned short* WoT = (unsigned short*)(w + 476053504ll);
  float* Wzt = (float*)(w + 478150656ll);
  float* Wrt = (float*)(w + 482344960ll);
  float* Wst = (float*)(w + 486539264ll);
  float* hbuf = (float*)(w + 490733568ll);
  float* zbuf = (float*)(w + 490995712ll);
  unsigned short* h_hi = (unsigned short*)(w + 491257856ll);
  unsigned short* h_lo = (unsigned short*)(w + 491388928ll);
  unsigned short* rh_hi = (unsigned short*)(w + 491520000ll);
  unsigned short* rh_lo = (unsigned short*)(w + 491651072ll);
  unsigned int* syncc = (unsigned int*)(w + 491782144ll);  // 128 epoch flags x 128B = 16KB

  float* out = (float*)d_out;
  float* hfin = out + 33554432;  // 64*512*1024

  hipLaunchKernelGGL(pack_split_kernel, dim3(16384), dim3(256), 0, stream,
                     inputs, Xhi, Xlo, 16777216);
  hipLaunchKernelGGL(packT_split_kernel, dim3(2048), dim3(256), 0, stream,
                     Wz + 1048576, WzxThi, WzxTlo, 9, 1024);
  hipLaunchKernelGGL(packT_split_kernel, dim3(2048), dim3(256), 0, stream,
                     Wr + 1048576, WrxThi, WrxTlo, 9, 1024);
  hipLaunchKernelGGL(packT_split_kernel, dim3(2048), dim3(256), 0, stream,
                     Ws + 1048576, WsxThi, WsxTlo, 9, 1024);
  hipLaunchKernelGGL(packT_bf16_kernel, dim3(4096), dim3(256), 0, stream, Wo, WoT, 10, 1024);
  hipLaunchKernelGGL(transpose1024_kernel, dim3(4096), dim3(256), 0, stream, Wz, Wzt);
  hipLaunchKernelGGL(transpose1024_kernel, dim3(4096), dim3(256), 0, stream, Wr, Wrt);
  hipLaunchKernelGGL(transpose1024_kernel, dim3(4096), dim3(256), 0, stream, Ws, Wst);

  hipLaunchKernelGGL(gemm_bf16x2_kernel, dim3(16, 512), dim3(256), 0, stream,
                     Xhi, Xlo, WzxThi, WzxTlo, bz, xz, 32768, 1024, 512);
  hipLaunchKernelGGL(gemm_bf16x2_kernel, dim3(16, 512), dim3(256), 0, stream,
                     Xhi, Xlo, WrxThi, WrxTlo, br, xr, 32768, 1024, 512);
  hipLaunchKernelGGL(gemm_bf16x2_kernel, dim3(16, 512), dim3(256), 0, stream,
                     Xhi, Xlo, WsxThi, WsxTlo, bs, xs, 32768, 1024, 512);

  // MFMA recurrence: 128 blocks, 132096 B dynamic LDS (4 x [16][1032] shorts)
  void* args[] = {&xz, &xr, &xs, &Wzt, &Wrt, &Wst, &hbuf, &zbuf,
                  &h_hi, &h_lo, &rh_hi, &rh_lo, &hs_bf, &hfin, &syncc};
  hipLaunchCooperativeKernel((const void*)recurrence_mfma_kernel, dim3(128), dim3(256),
                             args, 132096, stream);

  hipLaunchKernelGGL(gemm_bf16_kernel, dim3(16, 512), dim3(256), 0, stream,
                     hs_bf, WoT, bo, out, 32768, 1024, 1024, 1);
}